// Round 2
// baseline (83.486 us; speedup 1.0000x reference)
//
#include <hip/hip_runtime.h>

// out[b] = log( p0*(p1 + p2 - 2*p1*p2) + (1-p0)*p1*p2 ),  pi = exp(lp_i)
// Exact probability-space collapse of the reference log-space DAG.
__device__ __forceinline__ float eval_pc(float lp0, float lp1, float lp2) {
    float p0 = __expf(lp0);
    float p1 = __expf(lp1);
    float p2 = __expf(lp2);
    float p1p2  = p1 * p2;
    float inner = p1 + p2 - 2.0f * p1p2;          // p1(1-p2) + (1-p1)p2
    float tot   = fmaf(p0, inner, (1.0f - p0) * p1p2);
    return __logf(tot);
}

// Fully-coalesced version: 256-thread block handles 1024 batch elements.
// Input slice per block: 1024*3 floats = 768 float4s.
//   Phase 1: 3 unit-stride float4 loads per thread  -> LDS (no strided global access)
//   Phase 2: each thread reads its own 3 consecutive float4s from LDS
//            (12-dword lane stride: lanes i and i+8 alias -> 2-way, free on gfx950)
//   Phase 3: one coalesced float4 store (4 outputs/thread).
__global__ __launch_bounds__(256) void pc_eval_lds(const float4* __restrict__ in,
                                                   float4* __restrict__ out,
                                                   int nblk) {
    __shared__ float4 lds[768];   // 12 KB
    int blk = blockIdx.x;
    if (blk >= nblk) return;
    int t = threadIdx.x;
    int base4 = blk * 768;
#pragma unroll
    for (int k = 0; k < 3; ++k) {
        lds[k * 256 + t] = in[base4 + k * 256 + t];
    }
    __syncthreads();
    float4 a = lds[3 * t + 0];
    float4 b = lds[3 * t + 1];
    float4 c = lds[3 * t + 2];
    float4 o;
    o.x = eval_pc(a.x, a.y, a.z);
    o.y = eval_pc(a.w, b.x, b.y);
    o.z = eval_pc(b.z, b.w, c.x);
    o.w = eval_pc(c.y, c.z, c.w);
    out[blk * 256 + t] = o;
}

// Scalar tail for any remainder (unused at B = 2^22).
__global__ void pc_eval_tail(const float* __restrict__ in, float* __restrict__ out,
                             int start, int n) {
    int b = start + blockIdx.x * blockDim.x + threadIdx.x;
    if (b >= n) return;
    out[b] = eval_pc(in[3 * b + 0], in[3 * b + 1], in[3 * b + 2]);
}

extern "C" void kernel_launch(void* const* d_in, const int* in_sizes, int n_in,
                              void* d_out, int out_size, void* d_ws, size_t ws_size,
                              hipStream_t stream) {
    const float* lp = (const float*)d_in[0];
    float* out = (float*)d_out;
    int B = in_sizes[0] / 3;            // (B, 3) float32
    int nblk = B / 1024;                // full blocks of 1024 elements

    if (nblk > 0) {
        pc_eval_lds<<<nblk, 256, 0, stream>>>((const float4*)lp, (float4*)out, nblk);
    }
    int done = nblk * 1024;
    if (done < B) {
        int rem = B - done;
        pc_eval_tail<<<(rem + 255) / 256, 256, 0, stream>>>(lp, out, done, B);
    }
}

// Round 3
// 83.414 us; speedup vs baseline: 1.0009x; 1.0009x over previous
//
#include <hip/hip_runtime.h>

// out[b] = log( p0*(p1 + p2 - 2*p1*p2) + (1-p0)*p1*p2 ),  pi = exp(lp_i)
// Exact probability-space collapse of the reference log-space DAG:
//   data[5] = log(p1(1-p2) + (1-p1)p2)
//   data[7] = lp1 + lp2          (the -1000 sentinel underflows exactly)
//   out     = log(p0*data5_prob + (1-p0)*p1*p2)
__device__ __forceinline__ float eval_pc(float lp0, float lp1, float lp2) {
    float p0 = __expf(lp0);
    float p1 = __expf(lp1);
    float p2 = __expf(lp2);
    float p1p2  = p1 * p2;
    float inner = p1 + p2 - 2.0f * p1p2;          // p1(1-p2) + (1-p1)p2
    float tot   = fmaf(p0, inner, (1.0f - p0) * p1p2);
    return __logf(tot);
}

// 256-thread block handles 1024 batch elements (3072 input floats = 768 float4).
// Phase 1: 3 unit-stride float4 global loads per thread -> LDS (perfect coalescing).
// Phase 2: thread t computes elements {t, t+256, t+512, t+768}; scalar LDS reads
//          at 3-dword lane stride -> 2 lanes/bank (free on gfx950, m136).
// Phase 3: 4 scalar float stores, each a contiguous 256B wave store (coalesced).
__global__ __launch_bounds__(256) void pc_eval_lds2(const float4* __restrict__ in,
                                                    float* __restrict__ out,
                                                    int nblk) {
    __shared__ float lds[3072];   // 12 KB
    int blk = blockIdx.x;
    if (blk >= nblk) return;
    int t = threadIdx.x;
    int base4 = blk * 768;
    float4* lds4 = (float4*)lds;
#pragma unroll
    for (int k = 0; k < 3; ++k) {
        lds4[k * 256 + t] = in[base4 + k * 256 + t];
    }
    __syncthreads();
    int obase = blk * 1024;
#pragma unroll
    for (int m = 0; m < 4; ++m) {
        int e = t + 256 * m;                       // element within block
        float lp0 = lds[3 * e + 0];
        float lp1 = lds[3 * e + 1];
        float lp2 = lds[3 * e + 2];
        out[obase + e] = eval_pc(lp0, lp1, lp2);
    }
}

// Scalar tail for any remainder (unused at B = 2^22).
__global__ void pc_eval_tail(const float* __restrict__ in, float* __restrict__ out,
                             int start, int n) {
    int b = start + blockIdx.x * blockDim.x + threadIdx.x;
    if (b >= n) return;
    out[b] = eval_pc(in[3 * b + 0], in[3 * b + 1], in[3 * b + 2]);
}

extern "C" void kernel_launch(void* const* d_in, const int* in_sizes, int n_in,
                              void* d_out, int out_size, void* d_ws, size_t ws_size,
                              hipStream_t stream) {
    const float* lp = (const float*)d_in[0];
    float* out = (float*)d_out;
    int B = in_sizes[0] / 3;            // (B, 3) float32
    int nblk = B / 1024;                // full blocks of 1024 elements

    if (nblk > 0) {
        pc_eval_lds2<<<nblk, 256, 0, stream>>>((const float4*)lp, out, nblk);
    }
    int done = nblk * 1024;
    if (done < B) {
        int rem = B - done;
        pc_eval_tail<<<(rem + 255) / 256, 256, 0, stream>>>(lp, out, done, B);
    }
}